// Round 1
// baseline (302.434 us; speedup 1.0000x reference)
//
#include <hip/hip_runtime.h>
#include <hip/hip_bf16.h>

#define NB 2
#define NS 2048
#define NE 1024
#define NH 16
#define ND 64

typedef __attribute__((ext_vector_type(8))) short bf8_t;
typedef __attribute__((ext_vector_type(4))) float f32x4;

__device__ __forceinline__ short f2bf(float f) {
    union { float f; unsigned u; } v; v.f = f;
    return (short)((v.u + 0x7FFFu + ((v.u >> 16) & 1u)) >> 16);
}

// ---------------- Kernel 0: weight transpose + bf16 cast ----------------
// W[p][h][e][d] (fp32) -> wt[p][h][d][e] (bf16).  grid (3*NH, NE/64), block 256.
__global__ __launch_bounds__(256) void wt_kernel(
    const float* __restrict__ Wq, const float* __restrict__ Wk, const float* __restrict__ Wv,
    short* __restrict__ wt)
{
    const int p = blockIdx.x / NH, h = blockIdx.x % NH;
    const int e0 = blockIdx.y * 64;
    const float* W = (p == 0) ? Wq : (p == 1) ? Wk : Wv;
    const int t = threadIdx.x;
    const int er = t >> 2, dc = (t & 3) * 16;
    const float* src = W + ((size_t)h * NE + e0 + er) * ND + dc;
    short* dst = wt + (size_t)(p * NH + h) * ND * NE;
#pragma unroll
    for (int j = 0; j < 16; j += 4) {
        float4 x = *(const float4*)(src + j);
        dst[(size_t)(dc + j + 0) * NE + e0 + er] = f2bf(x.x);
        dst[(size_t)(dc + j + 1) * NE + e0 + er] = f2bf(x.y);
        dst[(size_t)(dc + j + 2) * NE + e0 + er] = f2bf(x.z);
        dst[(size_t)(dc + j + 3) * NE + e0 + er] = f2bf(x.w);
    }
}

// ---------------- Kernel 1: QKV projection GEMM ----------------
// out[p][b][h][s][d] bf16, 64x64 tile per block, K-step 32. grid (64, 48), block 256.
__global__ __launch_bounds__(256) void proj_kernel(
    const float* __restrict__ query, const float* __restrict__ key_in, const float* __restrict__ value_in,
    const float* __restrict__ bq, const float* __restrict__ bk, const float* __restrict__ bv,
    const short* __restrict__ wt, short* __restrict__ qkv_ws)
{
    __shared__ __attribute__((aligned(16))) short As[64][40];
    __shared__ __attribute__((aligned(16))) short Bs[64][40];

    const int p = blockIdx.y >> 4, h = blockIdx.y & 15;
    const float* in   = (p == 0) ? query : (p == 1) ? key_in : value_in;
    const float* bias = ((p == 0) ? bq : (p == 1) ? bk : bv) + h * ND;
    const short* Wt = wt + (size_t)(p * NH + h) * ND * NE;
    short* out = qkv_ws + (size_t)p * NB * NH * NS * ND;

    const int t = threadIdx.x;
    const int m0 = blockIdx.x * 64;
    const int lane = t & 63, w = t >> 6, l15 = lane & 15, g = lane >> 4, g8 = g * 8;

    f32x4 acc[4];
#pragma unroll
    for (int i = 0; i < 4; ++i) acc[i] = (f32x4){0.f, 0.f, 0.f, 0.f};

    const int arow = t >> 2, ac = (t & 3) * 8;
    const float* asrc = in + (size_t)(m0 + arow) * NE + ac;
    const short* bsrc = Wt + (size_t)arow * NE + ac;   // same 64x32 pattern for B

    for (int k0 = 0; k0 < NE; k0 += 32) {
        __syncthreads();
        float4 x0 = *(const float4*)(asrc + k0);
        float4 x1 = *(const float4*)(asrc + k0 + 4);
        bf8_t av;
        av[0] = f2bf(x0.x); av[1] = f2bf(x0.y); av[2] = f2bf(x0.z); av[3] = f2bf(x0.w);
        av[4] = f2bf(x1.x); av[5] = f2bf(x1.y); av[6] = f2bf(x1.z); av[7] = f2bf(x1.w);
        *(bf8_t*)&As[arow][ac] = av;
        *(bf8_t*)&Bs[arow][ac] = *(const bf8_t*)(bsrc + k0);
        __syncthreads();
        bf8_t af = *(const bf8_t*)&As[w * 16 + l15][g8];
#pragma unroll
        for (int nb = 0; nb < 4; ++nb) {
            bf8_t bf = *(const bf8_t*)&Bs[nb * 16 + l15][g8];
            acc[nb] = __builtin_amdgcn_mfma_f32_16x16x32_bf16(af, bf, acc[nb], 0, 0, 0);
        }
    }

#pragma unroll
    for (int nb = 0; nb < 4; ++nb)
#pragma unroll
        for (int r = 0; r < 4; ++r) {
            int row = m0 + w * 16 + g * 4 + r;
            int b = row >> 11, s = row & (NS - 1);
            int d = nb * 16 + l15;
            float val = acc[nb][r] + bias[d];
            out[(((size_t)b * NH + h) * NS + s) * ND + d] = f2bf(val);
        }
}

// ---------------- Kernel 2: causal flash attention ----------------
// grid (B*H, S/64), block 256 (4 waves, 16 q-rows each). O fp32 [B,S,E].
__global__ __launch_bounds__(256) void attn_kernel(
    const short* __restrict__ qkv_ws, float* __restrict__ O)
{
    __shared__ __attribute__((aligned(16))) short Qs[64][72];
    __shared__ __attribute__((aligned(16))) short Ks[64][72];
    __shared__ __attribute__((aligned(16))) short Vt[64][72];
    __shared__ __attribute__((aligned(16))) short Ps[4][16][72];

    const int bh = blockIdx.x;
    const int qt = (int)gridDim.y - 1 - (int)blockIdx.y;  // heavy tiles dispatched first
    const int b = bh >> 4, h = bh & 15;
    const int t = threadIdx.x, lane = t & 63, w = t >> 6;
    const int l15 = lane & 15, g = lane >> 4, g8 = g * 8;
    const size_t base = (size_t)bh * NS * ND;
    const short* q_ws = qkv_ws;
    const short* k_ws = qkv_ws + (size_t)NB * NH * NS * ND;
    const short* v_ws = k_ws + (size_t)NB * NH * NS * ND;
    const int q0 = qt * 64;

    const int srow = t >> 2, sc = (t & 3) * 16;
    {
        const short* src = q_ws + base + (size_t)(q0 + srow) * ND + sc;
        *(bf8_t*)&Qs[srow][sc] = *(const bf8_t*)src;
        *(bf8_t*)&Qs[srow][sc + 8] = *(const bf8_t*)(src + 8);
    }

    f32x4 oacc[4];
#pragma unroll
    for (int i = 0; i < 4; ++i) oacc[i] = (f32x4){0.f, 0.f, 0.f, 0.f};
    float m_i[4], l_i[4];
#pragma unroll
    for (int r = 0; r < 4; ++r) { m_i[r] = -1e30f; l_i[r] = 0.f; }

    const int qrow_base = q0 + w * 16 + g * 4;

    for (int tt = 0; tt <= qt; ++tt) {
        const int t0 = tt * 64;
        __syncthreads();
        {
            const short* ksrc = k_ws + base + (size_t)(t0 + srow) * ND + sc;
            *(bf8_t*)&Ks[srow][sc] = *(const bf8_t*)ksrc;
            *(bf8_t*)&Ks[srow][sc + 8] = *(const bf8_t*)(ksrc + 8);
            const short* vsrc = v_ws + base + (size_t)(t0 + srow) * ND + sc;
            bf8_t v0 = *(const bf8_t*)vsrc;
            bf8_t v1 = *(const bf8_t*)(vsrc + 8);
#pragma unroll
            for (int j = 0; j < 8; ++j) Vt[sc + j][srow] = v0[j];
#pragma unroll
            for (int j = 0; j < 8; ++j) Vt[sc + 8 + j][srow] = v1[j];
        }
        __syncthreads();

        // S = Q K^T  (per wave: 16 q-rows x 64 kv)
        f32x4 sa[4];
#pragma unroll
        for (int i = 0; i < 4; ++i) sa[i] = (f32x4){0.f, 0.f, 0.f, 0.f};
#pragma unroll
        for (int ks = 0; ks < 2; ++ks) {
            bf8_t af = *(const bf8_t*)&Qs[w * 16 + l15][ks * 32 + g8];
#pragma unroll
            for (int nb = 0; nb < 4; ++nb) {
                bf8_t bf = *(const bf8_t*)&Ks[nb * 16 + l15][ks * 32 + g8];
                sa[nb] = __builtin_amdgcn_mfma_f32_16x16x32_bf16(af, bf, sa[nb], 0, 0, 0);
            }
        }

        // scale + causal mask + row max
        const bool diag = (tt == qt);
        float mloc[4] = {-1e30f, -1e30f, -1e30f, -1e30f};
#pragma unroll
        for (int nb = 0; nb < 4; ++nb)
#pragma unroll
            for (int r = 0; r < 4; ++r) {
                float sv = sa[nb][r] * 0.125f;
                if (diag && (t0 + nb * 16 + l15 > qrow_base + r)) sv = -1e30f;
                sa[nb][r] = sv;
                mloc[r] = fmaxf(mloc[r], sv);
            }
#pragma unroll
        for (int off = 1; off < 16; off <<= 1)
#pragma unroll
            for (int r = 0; r < 4; ++r)
                mloc[r] = fmaxf(mloc[r], __shfl_xor(mloc[r], off));

        float alpha[4], rs[4];
#pragma unroll
        for (int r = 0; r < 4; ++r) {
            float mn = fmaxf(m_i[r], mloc[r]);
            alpha[r] = __expf(m_i[r] - mn);
            m_i[r] = mn;
            rs[r] = 0.f;
        }
#pragma unroll
        for (int nb = 0; nb < 4; ++nb)
#pragma unroll
            for (int r = 0; r < 4; ++r) {
                float pv = __expf(sa[nb][r] - m_i[r]);
                sa[nb][r] = pv;
                rs[r] += pv;
            }
#pragma unroll
        for (int off = 1; off < 16; off <<= 1)
#pragma unroll
            for (int r = 0; r < 4; ++r)
                rs[r] += __shfl_xor(rs[r], off);
#pragma unroll
        for (int r = 0; r < 4; ++r) l_i[r] = l_i[r] * alpha[r] + rs[r];
#pragma unroll
        for (int nb = 0; nb < 4; ++nb)
#pragma unroll
            for (int r = 0; r < 4; ++r) oacc[nb][r] *= alpha[r];

        // P -> bf16 -> LDS (wave-private) to re-layout into A-fragments
#pragma unroll
        for (int nb = 0; nb < 4; ++nb)
#pragma unroll
            for (int r = 0; r < 4; ++r)
                Ps[w][g * 4 + r][nb * 16 + l15] = f2bf(sa[nb][r]);
        __syncthreads();

        // O += P V
#pragma unroll
        for (int ks = 0; ks < 2; ++ks) {
            bf8_t pf = *(const bf8_t*)&Ps[w][l15][ks * 32 + g8];
#pragma unroll
            for (int nb = 0; nb < 4; ++nb) {
                bf8_t vf = *(const bf8_t*)&Vt[nb * 16 + l15][ks * 32 + g8];
                oacc[nb] = __builtin_amdgcn_mfma_f32_16x16x32_bf16(pf, vf, oacc[nb], 0, 0, 0);
            }
        }
    }

#pragma unroll
    for (int r = 0; r < 4; ++r) {
        float inv = 1.0f / l_i[r];
        int qg = qrow_base + r;
#pragma unroll
        for (int nb = 0; nb < 4; ++nb)
            O[((size_t)b * NS + qg) * NE + h * ND + nb * 16 + l15] = oacc[nb][r] * inv;
    }
}

// ---------------- Kernel 3: residual + custom LayerNorm ----------------
// one block per row. grid (B*S), block 256, 4 elems/thread.
__global__ __launch_bounds__(256) void ln_kernel(
    const float* __restrict__ Oin, const float* __restrict__ resid,
    const float* __restrict__ ln_scale, const float* __restrict__ ln_shift,
    float* __restrict__ out)
{
    __shared__ float red[8];
    const int row = blockIdx.x, t = threadIdx.x;
    const size_t basei = (size_t)row * NE + t * 4;
    float4 x = *(const float4*)(Oin + basei);
    float4 rr = *(const float4*)(resid + basei);
    x.x += rr.x; x.y += rr.y; x.z += rr.z; x.w += rr.w;
    float ps = x.x + x.y + x.z + x.w;
#pragma unroll
    for (int off = 32; off; off >>= 1) ps += __shfl_xor(ps, off);
    if ((t & 63) == 0) red[t >> 6] = ps;
    __syncthreads();
    const float mean = (red[0] + red[1] + red[2] + red[3]) * (1.0f / NE);
    const float dx0 = x.x - mean, dx1 = x.y - mean, dx2 = x.z - mean, dx3 = x.w - mean;
    float ss = dx0 * dx0 + dx1 * dx1 + dx2 * dx2 + dx3 * dx3;
#pragma unroll
    for (int off = 32; off; off >>= 1) ss += __shfl_xor(ss, off);
    if ((t & 63) == 0) red[4 + (t >> 6)] = ss;
    __syncthreads();
    const float stdv = sqrtf((red[4] + red[5] + red[6] + red[7]) * (1.0f / (NE - 1)));
    float4 sc = *(const float4*)(ln_scale + t * 4);
    float4 sh = *(const float4*)(ln_shift + t * 4);
    float4 o;
    o.x = sc.x * dx0 / (stdv + 1e-6f + sh.x);
    o.y = sc.y * dx1 / (stdv + 1e-6f + sh.y);
    o.z = sc.z * dx2 / (stdv + 1e-6f + sh.z);
    o.w = sc.w * dx3 / (stdv + 1e-6f + sh.w);
    *(float4*)(out + basei) = o;
}

extern "C" void kernel_launch(void* const* d_in, const int* in_sizes, int n_in,
                              void* d_out, int out_size, void* d_ws, size_t ws_size,
                              hipStream_t stream) {
    (void)in_sizes; (void)n_in; (void)out_size; (void)ws_size;
    const float* query    = (const float*)d_in[0];
    const float* key_in   = (const float*)d_in[1];
    const float* value_in = (const float*)d_in[2];
    const float* resid    = (const float*)d_in[3];
    const float* Wq = (const float*)d_in[4];
    const float* bq = (const float*)d_in[5];
    const float* Wk = (const float*)d_in[6];
    const float* bk = (const float*)d_in[7];
    const float* Wv = (const float*)d_in[8];
    const float* bv = (const float*)d_in[9];
    const float* ln_scale = (const float*)d_in[10];
    const float* ln_shift = (const float*)d_in[11];
    float* out = (float*)d_out;

    char* ws = (char*)d_ws;
    short* wt_ws  = (short*)ws;                       // 3*16*64*1024 bf16 = 6 MiB
    short* qkv_ws = (short*)(ws + (6u << 20));        // 3*2*16*2048*64 bf16 = 24 MiB
    float* O_ws   = (float*)(ws + (30u << 20));       // 2*2048*1024 fp32 = 16 MiB

    wt_kernel<<<dim3(3 * NH, NE / 64), 256, 0, stream>>>(Wq, Wk, Wv, wt_ws);
    proj_kernel<<<dim3(64, 48), 256, 0, stream>>>(query, key_in, value_in, bq, bk, bv, wt_ws, qkv_ws);
    attn_kernel<<<dim3(NB * NH, NS / 64), 256, 0, stream>>>(qkv_ws, O_ws);
    ln_kernel<<<dim3(NB * NS), 256, 0, stream>>>(O_ws, resid, ln_scale, ln_shift, out);
}

// Round 3
// 297.207 us; speedup vs baseline: 1.0176x; 1.0176x over previous
//
#include <hip/hip_runtime.h>
#include <hip/hip_bf16.h>

#define NB 2
#define NS 2048
#define NE 1024
#define NH 16
#define ND 64
#define MTOT (NB * NS)   // 4096

typedef __attribute__((ext_vector_type(8))) short bf8_t;
typedef __attribute__((ext_vector_type(4))) short bf4_t;
typedef __attribute__((ext_vector_type(4))) float f32x4;

__device__ __forceinline__ short f2bf(float f) {
    union { float f; unsigned u; } v; v.f = f;
    return (short)((v.u + 0x7FFFu + ((v.u >> 16) & 1u)) >> 16);
}

// async global->LDS, 16B per lane; LDS dest must be linear (base + lane*16)
#define GLOAD16(g, l) __builtin_amdgcn_global_load_lds( \
    (const __attribute__((address_space(1))) void*)(g), \
    (__attribute__((address_space(3))) void*)(l), 16, 0, 0)

// ---------------- Kernel A: one input fp32 -> bf16 (8 MB buffer) ----------------
__global__ __launch_bounds__(256) void conv_kernel(
    const float* __restrict__ src, short* __restrict__ out)
{
    const size_t nchunk = (size_t)MTOT * NE / 8;           // 8 elems per chunk
    const size_t stride = (size_t)gridDim.x * 256;
    for (size_t i = (size_t)blockIdx.x * 256 + threadIdx.x; i < nchunk; i += stride) {
        size_t e = i * 8;
        float4 x0 = *(const float4*)(src + e);
        float4 x1 = *(const float4*)(src + e + 4);
        bf8_t o;
        o[0] = f2bf(x0.x); o[1] = f2bf(x0.y); o[2] = f2bf(x0.z); o[3] = f2bf(x0.w);
        o[4] = f2bf(x1.x); o[5] = f2bf(x1.y); o[6] = f2bf(x1.z); o[7] = f2bf(x1.w);
        *(bf8_t*)(out + e) = o;
    }
}

// ---------------- Kernel B: weight transpose + bf16 cast ----------------
// W[p][h][e][d] fp32 -> wt[p][n=h*64+d][e] bf16 (i.e. B^T, [N][K]).
__global__ __launch_bounds__(256) void wt_kernel(
    const float* __restrict__ Wq, const float* __restrict__ Wk, const float* __restrict__ Wv,
    short* __restrict__ wt)
{
    const int p = blockIdx.x / NH, h = blockIdx.x % NH;
    const int e0 = blockIdx.y * 64;
    const float* W = (p == 0) ? Wq : (p == 1) ? Wk : Wv;
    const int t = threadIdx.x;
    const int er = t >> 2, dc = (t & 3) * 16;
    const float* src = W + ((size_t)h * NE + e0 + er) * ND + dc;
    short* dst = wt + (size_t)(p * NH + h) * ND * NE;
#pragma unroll
    for (int j = 0; j < 16; j += 4) {
        float4 x = *(const float4*)(src + j);
        dst[(size_t)(dc + j + 0) * NE + e0 + er] = f2bf(x.x);
        dst[(size_t)(dc + j + 1) * NE + e0 + er] = f2bf(x.y);
        dst[(size_t)(dc + j + 2) * NE + e0 + er] = f2bf(x.z);
        dst[(size_t)(dc + j + 3) * NE + e0 + er] = f2bf(x.w);
    }
}

// ---------------- Kernel C: QKV projection GEMM (m97 structure) ----------------
// 128x128 tile, BK=32, 4 waves (2x2 of 64x64), global_load_lds staging.
// p<2 out: [b][h][s][d] bf16.  p==2 out: [b][h][d][s] bf16 (pre-transposed V).
__global__ __launch_bounds__(256) void proj_kernel(
    const short* __restrict__ A, const short* __restrict__ Bm,
    const float* __restrict__ bias_all, int p, short* __restrict__ outp)
{
    __shared__ __attribute__((aligned(16))) short As[128 * 32];
    __shared__ __attribute__((aligned(16))) short Bs[128 * 32];

    const int m0 = blockIdx.x * 128, n0 = blockIdx.y * 128;
    const int t = threadIdx.x, lane = t & 63, w = t >> 6;
    const int l15 = lane & 15, g = lane >> 4;
    const int wr = w >> 1, wc = w & 1;

    const int srow = t >> 2, scol = (t & 3) * 8;
    const short* ag = A + (size_t)(m0 + srow) * NE + scol;
    const short* bg = Bm + (size_t)(n0 + srow) * NE + scol;
    short* asl = As + t * 8;       // chunk0; chunk1 at +2048 shorts (rows 64..127)
    short* bsl = Bs + t * 8;

    f32x4 acc[4][4];
#pragma unroll
    for (int i = 0; i < 4; ++i)
#pragma unroll
        for (int j = 0; j < 4; ++j) acc[i][j] = (f32x4){0.f, 0.f, 0.f, 0.f};

    for (int k0 = 0; k0 < NE; k0 += 32) {
        __syncthreads();
        GLOAD16(ag + k0, asl);
        GLOAD16(ag + k0 + (size_t)64 * NE, asl + 2048);
        GLOAD16(bg + k0, bsl);
        GLOAD16(bg + k0 + (size_t)64 * NE, bsl + 2048);
        __syncthreads();
        bf8_t af[4], bfr[4];
#pragma unroll
        for (int mf = 0; mf < 4; ++mf)
            af[mf] = *(const bf8_t*)&As[(wr * 64 + mf * 16 + l15) * 32 + g * 8];
#pragma unroll
        for (int nf = 0; nf < 4; ++nf)
            bfr[nf] = *(const bf8_t*)&Bs[(wc * 64 + nf * 16 + l15) * 32 + g * 8];
#pragma unroll
        for (int mf = 0; mf < 4; ++mf)
#pragma unroll
            for (int nf = 0; nf < 4; ++nf)
                acc[mf][nf] = __builtin_amdgcn_mfma_f32_16x16x32_bf16(af[mf], bfr[nf], acc[mf][nf], 0, 0, 0);
    }

    const int h = (n0 + wc * 64) >> 6;                      // head is wave-uniform
    const float* bias = bias_all + h * ND;

    if (p < 2) {
#pragma unroll
        for (int mf = 0; mf < 4; ++mf) {
            const int m = m0 + wr * 64 + mf * 16 + g * 4;
            const int bb = m >> 11, s = m & (NS - 1);
#pragma unroll
            for (int nf = 0; nf < 4; ++nf) {
                const int d = nf * 16 + l15;
                const float bi = bias[d];
                short* op = outp + (((size_t)bb * NH + h) * NS + s) * ND + d;
#pragma unroll
                for (int r = 0; r < 4; ++r)
                    op[(size_t)r * ND] = f2bf(acc[mf][nf][r] + bi);
            }
        }
    } else {
#pragma unroll
        for (int mf = 0; mf < 4; ++mf) {
            const int m = m0 + wr * 64 + mf * 16 + g * 4;
            const int bb = m >> 11, s = m & (NS - 1);
#pragma unroll
            for (int nf = 0; nf < 4; ++nf) {
                const int d = nf * 16 + l15;
                const float bi = bias[d];
                bf4_t pk;
#pragma unroll
                for (int r = 0; r < 4; ++r) pk[r] = f2bf(acc[mf][nf][r] + bi);
                *(bf4_t*)&outp[(((size_t)bb * NH + h) * ND + d) * NS + s] = pk;
            }
        }
    }
}

// ---------------- Kernel D: causal flash attention ----------------
// grid (B*H, S/64), block 256 (4 waves, 16 q-rows each). O fp32 [B,S,E].
__global__ __launch_bounds__(256) void attn_kernel(
    const short* __restrict__ q_ws, const short* __restrict__ k_ws,
    const short* __restrict__ vT_ws, float* __restrict__ O)
{
    __shared__ __attribute__((aligned(16))) short Qs[64][72];
    __shared__ __attribute__((aligned(16))) short Ks[64][72];
    __shared__ __attribute__((aligned(16))) short Vt[64][72];   // [d][kv]
    __shared__ __attribute__((aligned(16))) short Ps[4][16][72];

    const int bh = blockIdx.x;
    const int qt = (int)gridDim.y - 1 - (int)blockIdx.y;  // heavy tiles first
    const int b = bh >> 4, h = bh & 15;
    const int t = threadIdx.x, lane = t & 63, w = t >> 6;
    const int l15 = lane & 15, g = lane >> 4, g8 = g * 8;
    const size_t base = (size_t)bh * NS * ND;             // same for q_ws/k_ws/vT_ws
    const int q0 = qt * 64;

    const int srow = t >> 2, sc = (t & 3) * 16;
    {
        const short* src = q_ws + base + (size_t)(q0 + srow) * ND + sc;
        *(bf8_t*)&Qs[srow][sc] = *(const bf8_t*)src;
        *(bf8_t*)&Qs[srow][sc + 8] = *(const bf8_t*)(src + 8);
    }

    f32x4 oacc[4];
#pragma unroll
    for (int i = 0; i < 4; ++i) oacc[i] = (f32x4){0.f, 0.f, 0.f, 0.f};
    float m_i[4], l_i[4];
#pragma unroll
    for (int r = 0; r < 4; ++r) { m_i[r] = -1e30f; l_i[r] = 0.f; }

    const int qrow_base = q0 + w * 16 + g * 4;

    for (int tt = 0; tt <= qt; ++tt) {
        const int t0 = tt * 64;
        __syncthreads();
        {
            const short* ksrc = k_ws + base + (size_t)(t0 + srow) * ND + sc;
            *(bf8_t*)&Ks[srow][sc] = *(const bf8_t*)ksrc;
            *(bf8_t*)&Ks[srow][sc + 8] = *(const bf8_t*)(ksrc + 8);
            // V^T tile: rows are d, cols are kv
            const short* vsrc = vT_ws + base + (size_t)srow * NS + t0 + sc;
            *(bf8_t*)&Vt[srow][sc] = *(const bf8_t*)vsrc;
            *(bf8_t*)&Vt[srow][sc + 8] = *(const bf8_t*)(vsrc + 8);
        }
        __syncthreads();

        // S = Q K^T  (per wave: 16 q-rows x 64 kv)
        f32x4 sa[4];
#pragma unroll
        for (int i = 0; i < 4; ++i) sa[i] = (f32x4){0.f, 0.f, 0.f, 0.f};
#pragma unroll
        for (int ks = 0; ks < 2; ++ks) {
            bf8_t af = *(const bf8_t*)&Qs[w * 16 + l15][ks * 32 + g8];
#pragma unroll
            for (int nb = 0; nb < 4; ++nb) {
                bf8_t bf = *(const bf8_t*)&Ks[nb * 16 + l15][ks * 32 + g8];
                sa[nb] = __builtin_amdgcn_mfma_f32_16x16x32_bf16(af, bf, sa[nb], 0, 0, 0);
            }
        }

        // scale + causal mask + row max
        const bool diag = (tt == qt);
        float mloc[4] = {-1e30f, -1e30f, -1e30f, -1e30f};
#pragma unroll
        for (int nb = 0; nb < 4; ++nb)
#pragma unroll
            for (int r = 0; r < 4; ++r) {
                float sv = sa[nb][r] * 0.125f;
                if (diag && (t0 + nb * 16 + l15 > qrow_base + r)) sv = -1e30f;
                sa[nb][r] = sv;
                mloc[r] = fmaxf(mloc[r], sv);
            }
#pragma unroll
        for (int off = 1; off < 16; off <<= 1)
#pragma unroll
            for (int r = 0; r < 4; ++r)
                mloc[r] = fmaxf(mloc[r], __shfl_xor(mloc[r], off));

        float alpha[4], rs[4];
#pragma unroll
        for (int r = 0; r < 4; ++r) {
            float mn = fmaxf(m_i[r], mloc[r]);
            alpha[r] = __expf(m_i[r] - mn);
            m_i[r] = mn;
            rs[r] = 0.f;
        }
#pragma unroll
        for (int nb = 0; nb < 4; ++nb)
#pragma unroll
            for (int r = 0; r < 4; ++r) {
                float pv = __expf(sa[nb][r] - m_i[r]);
                sa[nb][r] = pv;
                rs[r] += pv;
            }
#pragma unroll
        for (int off = 1; off < 16; off <<= 1)
#pragma unroll
            for (int r = 0; r < 4; ++r)
                rs[r] += __shfl_xor(rs[r], off);
#pragma unroll
        for (int r = 0; r < 4; ++r) l_i[r] = l_i[r] * alpha[r] + rs[r];
#pragma unroll
        for (int nb = 0; nb < 4; ++nb)
#pragma unroll
            for (int r = 0; r < 4; ++r) oacc[nb][r] *= alpha[r];

        // P -> bf16 -> wave-private LDS (no block barrier needed)
#pragma unroll
        for (int nb = 0; nb < 4; ++nb)
#pragma unroll
            for (int r = 0; r < 4; ++r)
                Ps[w][g * 4 + r][nb * 16 + l15] = f2bf(sa[nb][r]);

        // O += P V
#pragma unroll
        for (int ks = 0; ks < 2; ++ks) {
            bf8_t pf = *(const bf8_t*)&Ps[w][l15][ks * 32 + g8];
#pragma unroll
            for (int nb = 0; nb < 4; ++nb) {
                bf8_t vf = *(const bf8_t*)&Vt[nb * 16 + l15][ks * 32 + g8];
                oacc[nb] = __builtin_amdgcn_mfma_f32_16x16x32_bf16(pf, vf, oacc[nb], 0, 0, 0);
            }
        }
    }

#pragma unroll
    for (int r = 0; r < 4; ++r) {
        float inv = 1.0f / l_i[r];
        int qg = qrow_base + r;
#pragma unroll
        for (int nb = 0; nb < 4; ++nb)
            O[((size_t)b * NS + qg) * NE + h * ND + nb * 16 + l15] = oacc[nb][r] * inv;
    }
}

// ---------------- Kernel E: residual + custom LayerNorm ----------------
__global__ __launch_bounds__(256) void ln_kernel(
    const float* __restrict__ Oin, const float* __restrict__ resid,
    const float* __restrict__ ln_scale, const float* __restrict__ ln_shift,
    float* __restrict__ out)
{
    __shared__ float red[8];
    const int row = blockIdx.x, t = threadIdx.x;
    const size_t basei = (size_t)row * NE + t * 4;
    float4 x = *(const float4*)(Oin + basei);
    float4 rr = *(const float4*)(resid + basei);
    x.x += rr.x; x.y += rr.y; x.z += rr.z; x.w += rr.w;
    float ps = x.x + x.y + x.z + x.w;
#pragma unroll
    for (int off = 32; off; off >>= 1) ps += __shfl_xor(ps, off);
    if ((t & 63) == 0) red[t >> 6] = ps;
    __syncthreads();
    const float mean = (red[0] + red[1] + red[2] + red[3]) * (1.0f / NE);
    const float dx0 = x.x - mean, dx1 = x.y - mean, dx2 = x.z - mean, dx3 = x.w - mean;
    float ss = dx0 * dx0 + dx1 * dx1 + dx2 * dx2 + dx3 * dx3;
#pragma unroll
    for (int off = 32; off; off >>= 1) ss += __shfl_xor(ss, off);
    if ((t & 63) == 0) red[4 + (t >> 6)] = ss;
    __syncthreads();
    const float stdv = sqrtf((red[4] + red[5] + red[6] + red[7]) * (1.0f / (NE - 1)));
    float4 sc = *(const float4*)(ln_scale + t * 4);
    float4 sh = *(const float4*)(ln_shift + t * 4);
    float4 o;
    o.x = sc.x * dx0 / (stdv + 1e-6f + sh.x);
    o.y = sc.y * dx1 / (stdv + 1e-6f + sh.y);
    o.z = sc.z * dx2 / (stdv + 1e-6f + sh.z);
    o.w = sc.w * dx3 / (stdv + 1e-6f + sh.w);
    *(float4*)(out + basei) = o;
}

extern "C" void kernel_launch(void* const* d_in, const int* in_sizes, int n_in,
                              void* d_out, int out_size, void* d_ws, size_t ws_size,
                              hipStream_t stream) {
    (void)in_sizes; (void)n_in; (void)out_size; (void)ws_size;
    const float* query    = (const float*)d_in[0];
    const float* key_in   = (const float*)d_in[1];
    const float* value_in = (const float*)d_in[2];
    const float* resid    = (const float*)d_in[3];
    const float* Wq = (const float*)d_in[4];
    const float* bq = (const float*)d_in[5];
    const float* Wk = (const float*)d_in[6];
    const float* bk = (const float*)d_in[7];
    const float* Wv = (const float*)d_in[8];
    const float* bv = (const float*)d_in[9];
    const float* ln_scale = (const float*)d_in[10];
    const float* ln_shift = (const float*)d_in[11];
    float* out = (float*)d_out;

    // layout (peak 38 MB; round-1's 46 MB worked):
    char* ws = (char*)d_ws;
    short* wt_ws = (short*)ws;                    // [0, 6) MB   dead after last proj
    short* in_bf = (short*)(ws + (6u << 20));     // [6, 14) MB  per-p staging, dead after last proj
    short* q_ws  = (short*)(ws + (14u << 20));    // [14,22)
    short* k_ws  = (short*)(ws + (22u << 20));    // [22,30)
    short* vT_ws = (short*)(ws + (30u << 20));    // [30,38)
    float* O_ws  = (float*)ws;                    // [0,16) aliases wt/in_bf (dead by attn)

    wt_kernel<<<dim3(3 * NH, NE / 64), 256, 0, stream>>>(Wq, Wk, Wv, wt_ws);

    const float* ins[3]   = {query, key_in, value_in};
    const float* biases[3] = {bq, bk, bv};
    short* outs[3] = {q_ws, k_ws, vT_ws};
    for (int p = 0; p < 3; ++p) {
        conv_kernel<<<1024, 256, 0, stream>>>(ins[p], in_bf);
        proj_kernel<<<dim3(MTOT / 128, NE / 128), 256, 0, stream>>>(
            in_bf, wt_ws + (size_t)p * NE * NE, biases[p], p, outs[p]);
    }

    attn_kernel<<<dim3(NB * NH, NS / 64), 256, 0, stream>>>(q_ws, k_ws, vT_ws, O_ws);
    ln_kernel<<<dim3(NB * NS), 256, 0, stream>>>(O_ws, resid, ln_scale, ln_shift, out);
}

// Round 4
// 284.985 us; speedup vs baseline: 1.0612x; 1.0429x over previous
//
#include <hip/hip_runtime.h>
#include <hip/hip_bf16.h>

#define NB 2
#define NS 2048
#define NE 1024
#define NH 16
#define ND 64
#define MTOT (NB * NS)   // 4096

// Q pre-scale: 1/sqrt(64) * log2(e)  -> softmax done in exp2 domain
#define QSCALE 0.18033688011112042f

typedef __attribute__((ext_vector_type(8))) short bf8_t;
typedef __attribute__((ext_vector_type(4))) short bf4_t;
typedef __attribute__((ext_vector_type(4))) float f32x4;
typedef __attribute__((ext_vector_type(16))) float f32x16;

__device__ __forceinline__ short f2bf(float f) {
    union { float f; unsigned u; } v; v.f = f;
    return (short)((v.u + 0x7FFFu + ((v.u >> 16) & 1u)) >> 16);
}

__device__ __forceinline__ unsigned cvtpk(float lo, float hi) {
    unsigned r;
    asm("v_cvt_pk_bf16_f32 %0, %1, %2" : "=v"(r) : "v"(lo), "v"(hi));
    return r;
}

__device__ __forceinline__ bf8_t mk4(unsigned a, unsigned b, unsigned c, unsigned d) {
    union { unsigned u[4]; bf8_t v; } t;
    t.u[0] = a; t.u[1] = b; t.u[2] = c; t.u[3] = d;
    return t.v;
}

// async global->LDS, 16B per lane; LDS dest must be linear (base + lane*16)
#define GLOAD16(g, l) __builtin_amdgcn_global_load_lds( \
    (const __attribute__((address_space(1))) void*)(g), \
    (__attribute__((address_space(3))) void*)(l), 16, 0, 0)

// ---------------- Kernel A: one input fp32 -> bf16 (8 MB buffer) ----------------
__global__ __launch_bounds__(256) void conv_kernel(
    const float* __restrict__ src, short* __restrict__ out)
{
    const size_t nchunk = (size_t)MTOT * NE / 8;
    const size_t stride = (size_t)gridDim.x * 256;
    for (size_t i = (size_t)blockIdx.x * 256 + threadIdx.x; i < nchunk; i += stride) {
        size_t e = i * 8;
        float4 x0 = *(const float4*)(src + e);
        float4 x1 = *(const float4*)(src + e + 4);
        bf8_t o;
        o[0] = f2bf(x0.x); o[1] = f2bf(x0.y); o[2] = f2bf(x0.z); o[3] = f2bf(x0.w);
        o[4] = f2bf(x1.x); o[5] = f2bf(x1.y); o[6] = f2bf(x1.z); o[7] = f2bf(x1.w);
        *(bf8_t*)(out + e) = o;
    }
}

// ---------------- Kernel B: weight transpose + bf16 cast ----------------
// W[p][h][e][d] fp32 -> wt[p][n=h*64+d][e] bf16 (B^T, [N][K]).
__global__ __launch_bounds__(256) void wt_kernel(
    const float* __restrict__ Wq, const float* __restrict__ Wk, const float* __restrict__ Wv,
    short* __restrict__ wt)
{
    const int p = blockIdx.x / NH, h = blockIdx.x % NH;
    const int e0 = blockIdx.y * 64;
    const float* W = (p == 0) ? Wq : (p == 1) ? Wk : Wv;
    const int t = threadIdx.x;
    const int er = t >> 2, dc = (t & 3) * 16;
    const float* src = W + ((size_t)h * NE + e0 + er) * ND + dc;
    short* dst = wt + (size_t)(p * NH + h) * ND * NE;
#pragma unroll
    for (int j = 0; j < 16; j += 4) {
        float4 x = *(const float4*)(src + j);
        dst[(size_t)(dc + j + 0) * NE + e0 + er] = f2bf(x.x);
        dst[(size_t)(dc + j + 1) * NE + e0 + er] = f2bf(x.y);
        dst[(size_t)(dc + j + 2) * NE + e0 + er] = f2bf(x.z);
        dst[(size_t)(dc + j + 3) * NE + e0 + er] = f2bf(x.w);
    }
}

// ---------------- Kernel C: projection GEMM (m97 structure) ----------------
// 128x128 tile, BK=32, 4 waves, global_load_lds staging.  p = pbase + blockIdx.z.
// p==0: Q out [b][h][s][d] scaled by QSCALE;  p==1: K out [b][h][s][d];
// p==2: V out [b][h][d][s] (pre-transposed).
__global__ __launch_bounds__(256) void proj_kernel(
    const short* __restrict__ in_bf, const short* __restrict__ wt,
    const float* __restrict__ bq, const float* __restrict__ bk, const float* __restrict__ bv,
    short* __restrict__ q_ws, short* __restrict__ k_ws, short* __restrict__ vT_ws,
    int pbase)
{
    __shared__ __attribute__((aligned(16))) short As[128 * 32];
    __shared__ __attribute__((aligned(16))) short Bs[128 * 32];

    const int z = blockIdx.z, p = pbase + z;
    const short* A = in_bf + (size_t)z * MTOT * NE;
    const short* Bm = wt + (size_t)p * NE * NE;
    const float* bias_all = (p == 0) ? bq : (p == 1) ? bk : bv;
    const float oscale = (p == 0) ? QSCALE : 1.0f;

    const int m0 = blockIdx.x * 128, n0 = blockIdx.y * 128;
    const int t = threadIdx.x, lane = t & 63, w = t >> 6;
    const int l15 = lane & 15, g = lane >> 4;
    const int wr = w >> 1, wc = w & 1;

    const int srow = t >> 2, scol = (t & 3) * 8;
    const short* ag = A + (size_t)(m0 + srow) * NE + scol;
    const short* bg = Bm + (size_t)(n0 + srow) * NE + scol;
    short* asl = As + t * 8;
    short* bsl = Bs + t * 8;

    f32x4 acc[4][4];
#pragma unroll
    for (int i = 0; i < 4; ++i)
#pragma unroll
        for (int j = 0; j < 4; ++j) acc[i][j] = (f32x4){0.f, 0.f, 0.f, 0.f};

    for (int k0 = 0; k0 < NE; k0 += 32) {
        __syncthreads();
        GLOAD16(ag + k0, asl);
        GLOAD16(ag + k0 + (size_t)64 * NE, asl + 2048);
        GLOAD16(bg + k0, bsl);
        GLOAD16(bg + k0 + (size_t)64 * NE, bsl + 2048);
        __syncthreads();
        bf8_t af[4], bfr[4];
#pragma unroll
        for (int mf = 0; mf < 4; ++mf)
            af[mf] = *(const bf8_t*)&As[(wr * 64 + mf * 16 + l15) * 32 + g * 8];
#pragma unroll
        for (int nf = 0; nf < 4; ++nf)
            bfr[nf] = *(const bf8_t*)&Bs[(wc * 64 + nf * 16 + l15) * 32 + g * 8];
#pragma unroll
        for (int mf = 0; mf < 4; ++mf)
#pragma unroll
            for (int nf = 0; nf < 4; ++nf)
                acc[mf][nf] = __builtin_amdgcn_mfma_f32_16x16x32_bf16(af[mf], bfr[nf], acc[mf][nf], 0, 0, 0);
    }

    const int h = (n0 + wc * 64) >> 6;
    const float* bias = bias_all + h * ND;

    if (p < 2) {
        short* outp = (p == 0) ? q_ws : k_ws;
#pragma unroll
        for (int mf = 0; mf < 4; ++mf) {
            const int m = m0 + wr * 64 + mf * 16 + g * 4;
            const int bb = m >> 11, s = m & (NS - 1);
#pragma unroll
            for (int nf = 0; nf < 4; ++nf) {
                const int d = nf * 16 + l15;
                const float bi = bias[d];
                short* op = outp + (((size_t)bb * NH + h) * NS + s) * ND + d;
#pragma unroll
                for (int r = 0; r < 4; ++r)
                    op[(size_t)r * ND] = f2bf((acc[mf][nf][r] + bi) * oscale);
            }
        }
    } else {
#pragma unroll
        for (int mf = 0; mf < 4; ++mf) {
            const int m = m0 + wr * 64 + mf * 16 + g * 4;
            const int bb = m >> 11, s = m & (NS - 1);
#pragma unroll
            for (int nf = 0; nf < 4; ++nf) {
                const int d = nf * 16 + l15;
                const float bi = bias[d];
                bf4_t pk;
#pragma unroll
                for (int r = 0; r < 4; ++r) pk[r] = f2bf(acc[mf][nf][r] + bi);
                *(bf4_t*)&vT_ws[(((size_t)bb * NH + h) * ND + d) * NS + s] = pk;
            }
        }
    }
}

// ---------------- Kernel D: barrier-free causal flash attention ----------------
// One warp = one job = 32 q-rows of one (b,h). 2048 jobs, heavy-first.
// 32x32x16 MFMA, swapped QK^T (S^T), transposed PV (O^T), all operands
// direct global->VGPR (KV is L2-resident). No __syncthreads in the kernel.
__global__ __launch_bounds__(256, 2) void attn_kernel(
    const short* __restrict__ q_ws, const short* __restrict__ k_ws,
    const short* __restrict__ vT_ws, float* __restrict__ O)
{
    __shared__ float oT[4][32][65];   // per-warp O^T transpose scratch (epilogue only)
    const int t = threadIdx.x, lane = t & 63, w = t >> 6;
    const int g = (int)blockIdx.x * 4 + w;     // job id
    const int jq = 63 - (g >> 5);              // q-tile index, heavy first
    const int bh = g & 31;
    const int b = bh >> 4, h = bh & 15;
    const int q0w = jq * 32;
    const int nt = (jq >> 1) + 1;              // # of 64-wide kv tiles
    const int l31 = lane & 31, hi = lane >> 5;
    const size_t base = (size_t)bh * NS * ND;

    // Q fragments (already scaled by QSCALE): B-frag, lane holds Q[q=l31][d=16s+8*hi+j]
    bf8_t Qf[4];
    {
        const short* qsrc = q_ws + base + (size_t)(q0w + l31) * ND + hi * 8;
#pragma unroll
        for (int s = 0; s < 4; ++s) Qf[s] = *(const bf8_t*)(qsrc + s * 16);
    }

    f32x16 Oa[2];
#pragma unroll
    for (int rb = 0; rb < 2; ++rb)
#pragma unroll
        for (int r = 0; r < 16; ++r) Oa[rb][r] = 0.f;
    float m_i = -1e30f, l_i = 0.f;
    const int qg = q0w + l31;

    for (int tt = 0; tt < nt; ++tt) {
        const int t0 = tt * 64;

        // K A-frags: lane holds K[kv=32c+l31][d=16s+8*hi+j]
        bf8_t Kf[2][4];
#pragma unroll
        for (int c = 0; c < 2; ++c) {
            const short* kp = k_ws + base + (size_t)(t0 + c * 32 + l31) * ND + hi * 8;
#pragma unroll
            for (int s = 0; s < 4; ++s) Kf[c][s] = *(const bf8_t*)(kp + s * 16);
        }
        // V^T A-frags: lane holds V^T[d=32rb+l31][kv=t0+16cs+8*hi+j]
        bf8_t Vf[4][2];
#pragma unroll
        for (int rb = 0; rb < 2; ++rb) {
            const short* vp = vT_ws + base + (size_t)(rb * 32 + l31) * NS + t0 + hi * 8;
#pragma unroll
            for (int cs = 0; cs < 4; ++cs) Vf[cs][rb] = *(const bf8_t*)(vp + cs * 16);
        }

        // S^T = K Q^T : D[row=kv-local][col=q=l31], log2 domain
        f32x16 Sv[2];
#pragma unroll
        for (int c = 0; c < 2; ++c) {
#pragma unroll
            for (int r = 0; r < 16; ++r) Sv[c][r] = 0.f;
#pragma unroll
            for (int s = 0; s < 4; ++s)
                Sv[c] = __builtin_amdgcn_mfma_f32_32x32x16_bf16(Kf[c][s], Qf[s], Sv[c], 0, 0, 0);
        }

        // causal mask (only the last tile straddles the diagonal)
        if (tt == nt - 1) {
#pragma unroll
            for (int c = 0; c < 2; ++c)
#pragma unroll
                for (int r = 0; r < 16; ++r) {
                    const int kvg = t0 + c * 32 + (r & 3) + 8 * (r >> 2) + 4 * hi;
                    if (kvg > qg) Sv[c][r] = -1e30f;
                }
        }

        // row max: 31 in-lane + cross-half exchange
        float mloc = Sv[0][0];
#pragma unroll
        for (int r = 1; r < 16; ++r) mloc = fmaxf(mloc, Sv[0][r]);
#pragma unroll
        for (int r = 0; r < 16; ++r) mloc = fmaxf(mloc, Sv[1][r]);
        mloc = fmaxf(mloc, __shfl_xor(mloc, 32));

        // defer-max (T13): rescale only when max grew past threshold (log2 units)
        if (__any(mloc > m_i + 11.0f)) {
            const float mn = fmaxf(m_i, mloc);
            const float al = exp2f(m_i - mn);
            m_i = mn;
            l_i *= al;
#pragma unroll
            for (int rb = 0; rb < 2; ++rb)
#pragma unroll
                for (int r = 0; r < 16; ++r) Oa[rb][r] *= al;
        }

        // P = exp2(S - m), row sum, pack to bf16 PV B-frags in-register (T12)
        float rs = 0.f;
        bf8_t Pf[2][2];
#pragma unroll
        for (int c = 0; c < 2; ++c) {
#pragma unroll
            for (int r = 0; r < 16; ++r) {
                const float pv = exp2f(Sv[c][r] - m_i);
                Sv[c][r] = pv;
                rs += pv;
            }
            unsigned wv[8], xv[8];
#pragma unroll
            for (int i = 0; i < 8; ++i) wv[i] = cvtpk(Sv[c][2 * i], Sv[c][2 * i + 1]);
#pragma unroll
            for (int i = 0; i < 8; ++i) xv[i] = __shfl_xor(wv[i], 32);
            Pf[c][0] = hi ? mk4(xv[2], xv[3], wv[2], wv[3]) : mk4(wv[0], wv[1], xv[0], xv[1]);
            Pf[c][1] = hi ? mk4(xv[6], xv[7], wv[6], wv[7]) : mk4(wv[4], wv[5], xv[4], xv[5]);
        }
        rs += __shfl_xor(rs, 32);
        l_i += rs;

        // O^T += V^T P^T : D[row=d-local][col=q]
#pragma unroll
        for (int cs = 0; cs < 4; ++cs)
#pragma unroll
            for (int rb = 0; rb < 2; ++rb)
                Oa[rb] = __builtin_amdgcn_mfma_f32_32x32x16_bf16(Vf[cs][rb], Pf[cs >> 1][cs & 1], Oa[rb], 0, 0, 0);
    }

    // epilogue: normalize, transpose via per-warp LDS, coalesced f32 stores
    const float inv = 1.0f / l_i;
#pragma unroll
    for (int rb = 0; rb < 2; ++rb)
#pragma unroll
        for (int r = 0; r < 16; ++r)
            oT[w][l31][rb * 32 + (r & 3) + 8 * (r >> 2) + 4 * hi] = Oa[rb][r] * inv;

    asm volatile("s_waitcnt lgkmcnt(0)" ::: "memory");

#pragma unroll
    for (int p4 = 0; p4 < 4; ++p4) {
        const int qr = p4 * 8 + (lane >> 3), d8 = (lane & 7) * 8;
        const float4 a0 = *(const float4*)&oT[w][qr][d8];
        const float4 a1 = *(const float4*)&oT[w][qr][d8 + 4];
        float* op = O + ((size_t)b * NS + q0w + qr) * NE + h * 64 + d8;
        *(float4*)op = a0;
        *(float4*)(op + 4) = a1;
    }
}

// ---------------- Kernel E: residual + custom LayerNorm ----------------
__global__ __launch_bounds__(256) void ln_kernel(
    const float* __restrict__ Oin, const float* __restrict__ resid,
    const float* __restrict__ ln_scale, const float* __restrict__ ln_shift,
    float* __restrict__ out)
{
    __shared__ float red[8];
    const int row = blockIdx.x, t = threadIdx.x;
    const size_t basei = (size_t)row * NE + t * 4;
    float4 x = *(const float4*)(Oin + basei);
    float4 rr = *(const float4*)(resid + basei);
    x.x += rr.x; x.y += rr.y; x.z += rr.z; x.w += rr.w;
    float ps = x.x + x.y + x.z + x.w;
#pragma unroll
    for (int off = 32; off; off >>= 1) ps += __shfl_xor(ps, off);
    if ((t & 63) == 0) red[t >> 6] = ps;
    __syncthreads();
    const float mean = (red[0] + red[1] + red[2] + red[3]) * (1.0f / NE);
    const float dx0 = x.x - mean, dx1 = x.y - mean, dx2 = x.z - mean, dx3 = x.w - mean;
    float ss = dx0 * dx0 + dx1 * dx1 + dx2 * dx2 + dx3 * dx3;
#pragma unroll
    for (int off = 32; off; off >>= 1) ss += __shfl_xor(ss, off);
    if ((t & 63) == 0) red[4 + (t >> 6)] = ss;
    __syncthreads();
    const float stdv = sqrtf((red[4] + red[5] + red[6] + red[7]) * (1.0f / (NE - 1)));
    float4 sc = *(const float4*)(ln_scale + t * 4);
    float4 sh = *(const float4*)(ln_shift + t * 4);
    float4 o;
    o.x = sc.x * dx0 / (stdv + 1e-6f + sh.x);
    o.y = sc.y * dx1 / (stdv + 1e-6f + sh.y);
    o.z = sc.z * dx2 / (stdv + 1e-6f + sh.z);
    o.w = sc.w * dx3 / (stdv + 1e-6f + sh.w);
    *(float4*)(out + basei) = o;
}

extern "C" void kernel_launch(void* const* d_in, const int* in_sizes, int n_in,
                              void* d_out, int out_size, void* d_ws, size_t ws_size,
                              hipStream_t stream) {
    (void)in_sizes; (void)n_in; (void)out_size; (void)ws_size;
    const float* query    = (const float*)d_in[0];
    const float* key_in   = (const float*)d_in[1];
    const float* value_in = (const float*)d_in[2];
    const float* resid    = (const float*)d_in[3];
    const float* Wq = (const float*)d_in[4];
    const float* bq = (const float*)d_in[5];
    const float* Wk = (const float*)d_in[6];
    const float* bk = (const float*)d_in[7];
    const float* Wv = (const float*)d_in[8];
    const float* bv = (const float*)d_in[9];
    const float* ln_scale = (const float*)d_in[10];
    const float* ln_shift = (const float*)d_in[11];
    float* out = (float*)d_out;

    // workspace layout (peak 46 MB, proven in round 1):
    char* ws = (char*)d_ws;
    short* wt_ws = (short*)ws;                    // [0, 6) MB   dead after proj V
    short* in_bf = (short*)(ws + (6u << 20));     // [6,22) MB   two 8MB slots, dead after proj V
    short* q_ws  = (short*)(ws + (22u << 20));    // [22,30)
    short* k_ws  = (short*)(ws + (30u << 20));    // [30,38)
    short* vT_ws = (short*)(ws + (38u << 20));    // [38,46)
    float* O_ws  = (float*)ws;                    // [0,16) aliases wt/in_bf (dead by attn)

    short* slot0 = in_bf;
    short* slot1 = in_bf + (size_t)MTOT * NE;

    wt_kernel<<<dim3(3 * NH, NE / 64), 256, 0, stream>>>(Wq, Wk, Wv, wt_ws);

    conv_kernel<<<1024, 256, 0, stream>>>(query, slot0);
    conv_kernel<<<1024, 256, 0, stream>>>(key_in, slot1);
    proj_kernel<<<dim3(MTOT / 128, NE / 128, 2), 256, 0, stream>>>(
        in_bf, wt_ws, bq, bk, bv, q_ws, k_ws, vT_ws, 0);

    conv_kernel<<<1024, 256, 0, stream>>>(value_in, slot0);
    proj_kernel<<<dim3(MTOT / 128, NE / 128, 1), 256, 0, stream>>>(
        in_bf, wt_ws, bq, bk, bv, q_ws, k_ws, vT_ws, 2);

    attn_kernel<<<512, 256, 0, stream>>>(q_ws, k_ws, vT_ws, O_ws);
    ln_kernel<<<dim3(NB * NS), 256, 0, stream>>>(O_ws, resid, ln_scale, ln_shift, out);
}

// Round 5
// 279.190 us; speedup vs baseline: 1.0833x; 1.0208x over previous
//
#include <hip/hip_runtime.h>
#include <hip/hip_bf16.h>

#define NB 2
#define NS 2048
#define NE 1024
#define NH 16
#define ND 64
#define MTOT (NB * NS)   // 4096

// Q pre-scale: 1/sqrt(64) * log2(e)  -> softmax in exp2 domain
#define QSCALE 0.18033688011112042f

typedef __attribute__((ext_vector_type(8))) short bf8_t;
typedef __attribute__((ext_vector_type(4))) short bf4_t;
typedef __attribute__((ext_vector_type(4))) float f32x4;
typedef __attribute__((ext_vector_type(16))) float f32x16;

__device__ __forceinline__ short f2bf(float f) {
    union { float f; unsigned u; } v; v.f = f;
    return (short)((v.u + 0x7FFFu + ((v.u >> 16) & 1u)) >> 16);
}
__device__ __forceinline__ float b2f(short s) {
    union { unsigned u; float f; } v; v.u = ((unsigned)(unsigned short)s) << 16;
    return v.f;
}
__device__ __forceinline__ unsigned cvtpk(float lo, float hi) {
    unsigned r;
    asm("v_cvt_pk_bf16_f32 %0, %1, %2" : "=v"(r) : "v"(lo), "v"(hi));
    return r;
}
__device__ __forceinline__ bf8_t mk4(unsigned a, unsigned b, unsigned c, unsigned d) {
    union { unsigned u[4]; bf8_t v; } t;
    t.u[0] = a; t.u[1] = b; t.u[2] = c; t.u[3] = d;
    return t.v;
}

// async global->LDS, 16B per lane; LDS dest must be linear (base + lane*16)
#define GLOAD16(g, l) __builtin_amdgcn_global_load_lds( \
    (const __attribute__((address_space(1))) void*)(g), \
    (__attribute__((address_space(3))) void*)(l), 16, 0, 0)

// ---------------- Kernel B: weight transpose + bf16 cast ----------------
// W[p][h][e][d] fp32 -> wt[p][n=h*64+d][e] bf16 (B^T, [N][K]).
__global__ __launch_bounds__(256) void wt_kernel(
    const float* __restrict__ Wq, const float* __restrict__ Wk, const float* __restrict__ Wv,
    short* __restrict__ wt)
{
    const int p = blockIdx.x / NH, h = blockIdx.x % NH;
    const int e0 = blockIdx.y * 64;
    const float* W = (p == 0) ? Wq : (p == 1) ? Wk : Wv;
    const int t = threadIdx.x;
    const int er = t >> 2, dc = (t & 3) * 16;
    const float* src = W + ((size_t)h * NE + e0 + er) * ND + dc;
    short* dst = wt + (size_t)(p * NH + h) * ND * NE;
#pragma unroll
    for (int j = 0; j < 16; j += 4) {
        float4 x = *(const float4*)(src + j);
        dst[(size_t)(dc + j + 0) * NE + e0 + er] = f2bf(x.x);
        dst[(size_t)(dc + j + 1) * NE + e0 + er] = f2bf(x.y);
        dst[(size_t)(dc + j + 2) * NE + e0 + er] = f2bf(x.z);
        dst[(size_t)(dc + j + 3) * NE + e0 + er] = f2bf(x.w);
    }
}

// ---------------- Kernel C: fused conv+projection GEMM ----------------
// A fp32 [4096][1024] staged via global_load_lds (XOR-swizzled source cols),
// converted to bf16 at frag-load time. 128x128 tile, BK=32, 4 waves.
// grid (32, 8, 3): z = p.  p0: Q [b][h][s][d] * QSCALE; p1: K; p2: V^T [b][h][d][s].
__global__ __launch_bounds__(256) void proj_kernel(
    const float* __restrict__ query, const float* __restrict__ key_in, const float* __restrict__ value_in,
    const short* __restrict__ wt,
    const float* __restrict__ bq, const float* __restrict__ bk, const float* __restrict__ bv,
    short* __restrict__ q_ws, short* __restrict__ k_ws, short* __restrict__ vT_ws)
{
    __shared__ __attribute__((aligned(16))) float Asf[128 * 32];   // 16 KB
    __shared__ __attribute__((aligned(16))) short Bs[128 * 32];    // 8 KB

    const int p = blockIdx.z;
    const float* A = (p == 0) ? query : (p == 1) ? key_in : value_in;
    const short* Bm = wt + (size_t)p * NE * NE;
    const float* bias_all = (p == 0) ? bq : (p == 1) ? bk : bv;
    const float oscale = (p == 0) ? QSCALE : 1.0f;

    const int m0 = blockIdx.x * 128, n0 = blockIdx.y * 128;
    const int t = threadIdx.x, lane = t & 63, w = t >> 6;
    const int l15 = lane & 15, g = lane >> 4, g8 = g * 8;
    const int wr = w >> 1, wc = w & 1;

    // A staging: 4 x 16B chunks/thread; source col pre-swizzled (rule #21: swizzle
    // source + read, keep LDS dest linear for global_load_lds)
    const int arow = t >> 3;
    const int acol = ((t & 7) * 4) ^ ((arow & 3) << 3);
    const float* ag = A + (size_t)(m0 + arow) * NE + acol;
    float* asl = Asf + t * 4;
    // B staging: 2 x 16B chunks/thread, same swizzle in shorts
    const int brow = t >> 2;
    const int bcol = ((t & 3) * 8) ^ ((brow & 3) << 3);
    const short* bg = Bm + (size_t)(n0 + brow) * NE + bcol;
    short* bsl = Bs + t * 8;

    f32x4 acc[4][4];
#pragma unroll
    for (int i = 0; i < 4; ++i)
#pragma unroll
        for (int j = 0; j < 4; ++j) acc[i][j] = (f32x4){0.f, 0.f, 0.f, 0.f};

    const int aswz = (l15 & 3) << 3;   // row&3 == l15&3 for frag rows

    for (int k0 = 0; k0 < NE; k0 += 32) {
        __syncthreads();
        GLOAD16(ag + k0, asl);
        GLOAD16(ag + k0 + (size_t)32 * NE, asl + 1024);
        GLOAD16(ag + k0 + (size_t)64 * NE, asl + 2048);
        GLOAD16(ag + k0 + (size_t)96 * NE, asl + 3072);
        GLOAD16(bg + k0, bsl);
        GLOAD16(bg + k0 + (size_t)64 * NE, bsl + 2048);
        __syncthreads();

        bf8_t af[4], bfr[4];
#pragma unroll
        for (int mf = 0; mf < 4; ++mf) {
            const int ar = wr * 64 + mf * 16 + l15;
            const float* ap = &Asf[ar * 32 + (g8 ^ aswz)];
            f32x4 v0 = *(const f32x4*)ap;
            f32x4 v1 = *(const f32x4*)(ap + 4);
            af[mf] = mk4(cvtpk(v0[0], v0[1]), cvtpk(v0[2], v0[3]),
                         cvtpk(v1[0], v1[1]), cvtpk(v1[2], v1[3]));
        }
#pragma unroll
        for (int nf = 0; nf < 4; ++nf) {
            const int br = wc * 64 + nf * 16 + l15;
            bfr[nf] = *(const bf8_t*)&Bs[br * 32 + (g8 ^ aswz)];
        }
#pragma unroll
        for (int mf = 0; mf < 4; ++mf)
#pragma unroll
            for (int nf = 0; nf < 4; ++nf)
                acc[mf][nf] = __builtin_amdgcn_mfma_f32_16x16x32_bf16(af[mf], bfr[nf], acc[mf][nf], 0, 0, 0);
    }

    const int h = (n0 + wc * 64) >> 6;
    const float* bias = bias_all + h * ND;

    if (p < 2) {
        short* outp = (p == 0) ? q_ws : k_ws;
#pragma unroll
        for (int mf = 0; mf < 4; ++mf) {
            const int m = m0 + wr * 64 + mf * 16 + g * 4;
            const int bb = m >> 11, s = m & (NS - 1);
#pragma unroll
            for (int nf = 0; nf < 4; ++nf) {
                const int d = nf * 16 + l15;
                const float bi = bias[d];
                short* op = outp + (((size_t)bb * NH + h) * NS + s) * ND + d;
#pragma unroll
                for (int r = 0; r < 4; ++r)
                    op[(size_t)r * ND] = f2bf((acc[mf][nf][r] + bi) * oscale);
            }
        }
    } else {
#pragma unroll
        for (int mf = 0; mf < 4; ++mf) {
            const int m = m0 + wr * 64 + mf * 16 + g * 4;
            const int bb = m >> 11, s = m & (NS - 1);
#pragma unroll
            for (int nf = 0; nf < 4; ++nf) {
                const int d = nf * 16 + l15;
                const float bi = bias[d];
                bf4_t pk;
#pragma unroll
                for (int r = 0; r < 4; ++r) pk[r] = f2bf(acc[mf][nf][r] + bi);
                *(bf4_t*)&vT_ws[(((size_t)bb * NH + h) * ND + d) * NS + s] = pk;
            }
        }
    }
}

// ---------------- Kernel D: split-KV causal flash attention ----------------
// 4096 warp-jobs: (jq, half, bh). Each job does half the KV tiles of q-tile jq,
// writes UNNORMALIZED bf16 partial O + (m,l). grid 1024 x 256, heavy-first.
__global__ __launch_bounds__(256) void attn_kernel(
    const short* __restrict__ q_ws, const short* __restrict__ k_ws,
    const short* __restrict__ vT_ws, short* __restrict__ oPart, float2* __restrict__ ml)
{
    __shared__ float oT[4][32][33];   // per-warp epilogue transpose (16.9 KB)
    const int t = threadIdx.x, lane = t & 63, w = t >> 6;
    const int jj = (int)blockIdx.x * 4 + w;
    const int j2 = jj >> 5;                    // 0..127, heavy-first
    const int jq = 63 - (j2 >> 1);
    const int half = j2 & 1;
    const int bh = jj & 31;
    const int b = bh >> 4, h = bh & 15;
    const int q0w = jq * 32;
    const int ntot = (jq >> 1) + 1;            // KV tiles covering this q-tile
    const int mid = ntot >> 1;
    const int ts = half ? mid : 0;
    const int te = half ? ntot : mid;
    const int l31 = lane & 31, hi = lane >> 5;
    const size_t base = (size_t)bh * NS * ND;

    // Q B-frags (pre-scaled): lane holds Q[q=l31][d=16s+8*hi+j]
    bf8_t Qf[4];
    {
        const short* qsrc = q_ws + base + (size_t)(q0w + l31) * ND + hi * 8;
#pragma unroll
        for (int s = 0; s < 4; ++s) Qf[s] = *(const bf8_t*)(qsrc + s * 16);
    }

    f32x16 Oa[2];
#pragma unroll
    for (int rb = 0; rb < 2; ++rb)
#pragma unroll
        for (int r = 0; r < 16; ++r) Oa[rb][r] = 0.f;
    float m_i = -1e30f, l_i = 0.f;
    const int qg = q0w + l31;

    for (int tt = ts; tt < te; ++tt) {
        const int t0 = tt * 64;

        bf8_t Kf[2][4];
#pragma unroll
        for (int c = 0; c < 2; ++c) {
            const short* kp = k_ws + base + (size_t)(t0 + c * 32 + l31) * ND + hi * 8;
#pragma unroll
            for (int s = 0; s < 4; ++s) Kf[c][s] = *(const bf8_t*)(kp + s * 16);
        }
        bf8_t Vf[4][2];
#pragma unroll
        for (int rb = 0; rb < 2; ++rb) {
            const short* vp = vT_ws + base + (size_t)(rb * 32 + l31) * NS + t0 + hi * 8;
#pragma unroll
            for (int cs = 0; cs < 4; ++cs) Vf[cs][rb] = *(const bf8_t*)(vp + cs * 16);
        }

        // S^T = K Q^T (log2 domain)
        f32x16 Sv[2];
#pragma unroll
        for (int c = 0; c < 2; ++c) {
#pragma unroll
            for (int r = 0; r < 16; ++r) Sv[c][r] = 0.f;
#pragma unroll
            for (int s = 0; s < 4; ++s)
                Sv[c] = __builtin_amdgcn_mfma_f32_32x32x16_bf16(Kf[c][s], Qf[s], Sv[c], 0, 0, 0);
        }

        if (tt == ntot - 1) {   // only the global last tile straddles the diagonal
#pragma unroll
            for (int c = 0; c < 2; ++c)
#pragma unroll
                for (int r = 0; r < 16; ++r) {
                    const int kvg = t0 + c * 32 + (r & 3) + 8 * (r >> 2) + 4 * hi;
                    if (kvg > qg) Sv[c][r] = -1e30f;
                }
        }

        float mloc = Sv[0][0];
#pragma unroll
        for (int r = 1; r < 16; ++r) mloc = fmaxf(mloc, Sv[0][r]);
#pragma unroll
        for (int r = 0; r < 16; ++r) mloc = fmaxf(mloc, Sv[1][r]);
        mloc = fmaxf(mloc, __shfl_xor(mloc, 32));

        if (__any(mloc > m_i + 11.0f)) {   // defer-max (T13)
            const float mn = fmaxf(m_i, mloc);
            const float al = exp2f(m_i - mn);
            m_i = mn;
            l_i *= al;
#pragma unroll
            for (int rb = 0; rb < 2; ++rb)
#pragma unroll
                for (int r = 0; r < 16; ++r) Oa[rb][r] *= al;
        }

        float rs = 0.f;
        bf8_t Pf[2][2];
#pragma unroll
        for (int c = 0; c < 2; ++c) {
#pragma unroll
            for (int r = 0; r < 16; ++r) {
                const float pv = exp2f(Sv[c][r] - m_i);
                Sv[c][r] = pv;
                rs += pv;
            }
            unsigned wv[8], xv[8];
#pragma unroll
            for (int i = 0; i < 8; ++i) wv[i] = cvtpk(Sv[c][2 * i], Sv[c][2 * i + 1]);
#pragma unroll
            for (int i = 0; i < 8; ++i) xv[i] = __shfl_xor(wv[i], 32);
            Pf[c][0] = hi ? mk4(xv[2], xv[3], wv[2], wv[3]) : mk4(wv[0], wv[1], xv[0], xv[1]);
            Pf[c][1] = hi ? mk4(xv[6], xv[7], wv[6], wv[7]) : mk4(wv[4], wv[5], xv[4], xv[5]);
        }
        rs += __shfl_xor(rs, 32);
        l_i += rs;

        // O^T += V^T P^T
#pragma unroll
        for (int cs = 0; cs < 4; ++cs)
#pragma unroll
            for (int rb = 0; rb < 2; ++rb)
                Oa[rb] = __builtin_amdgcn_mfma_f32_32x32x16_bf16(Vf[cs][rb], Pf[cs >> 1][cs & 1], Oa[rb], 0, 0, 0);
    }

    // partial state
    if (hi == 0) ml[((size_t)half * 32 + bh) * NS + qg] = (float2){m_i, l_i};

    // unnormalized partial O -> bf16, transposed via per-warp LDS (two 32x32 passes)
    short* obase = oPart + (size_t)half * MTOT * NE;
#pragma unroll
    for (int rb = 0; rb < 2; ++rb) {
#pragma unroll
        for (int r = 0; r < 16; ++r)
            oT[w][l31][(r & 3) + 8 * (r >> 2) + 4 * hi] = Oa[rb][r];
        asm volatile("s_waitcnt lgkmcnt(0)" ::: "memory");
        const int q = lane >> 1, dhalf = (lane & 1) * 16;
        const float* src = &oT[w][q][dhalf];
        float4 a0 = *(const float4*)(src);
        float4 a1 = *(const float4*)(src + 4);
        float4 a2 = *(const float4*)(src + 8);
        float4 a3 = *(const float4*)(src + 12);
        short* dst = obase + ((size_t)b * NS + q0w + q) * NE + h * 64 + rb * 32 + dhalf;
        *(bf8_t*)dst = mk4(cvtpk(a0.x, a0.y), cvtpk(a0.z, a0.w), cvtpk(a1.x, a1.y), cvtpk(a1.z, a1.w));
        *(bf8_t*)(dst + 8) = mk4(cvtpk(a2.x, a2.y), cvtpk(a2.z, a2.w), cvtpk(a3.x, a3.y), cvtpk(a3.z, a3.w));
        asm volatile("s_waitcnt lgkmcnt(0)" ::: "memory");
    }
}

// ---------------- Kernel E: combine + residual + custom LayerNorm ----------------
// one block per row (b,s). Combines the two KV-half partials, then LN.
__global__ __launch_bounds__(256) void ln_kernel(
    const short* __restrict__ oPart, const float2* __restrict__ ml,
    const float* __restrict__ resid,
    const float* __restrict__ ln_scale, const float* __restrict__ ln_shift,
    float* __restrict__ out)
{
    __shared__ float red[8];
    __shared__ float wtab[16][2];
    const int row = blockIdx.x, t = threadIdx.x;
    const int b = row >> 11, s = row & (NS - 1);

    if (t < 16) {
        const float2 a = ml[((size_t)b * 16 + t) * NS + s];            // half 0
        const float2 c = ml[((size_t)(32 + b * 16 + t)) * NS + s];     // half 1
        const float m = fmaxf(a.x, c.x);
        const float w0 = exp2f(a.x - m), w1 = exp2f(c.x - m);
        const float inv = 1.0f / (w0 * a.y + w1 * c.y);
        wtab[t][0] = w0 * inv;
        wtab[t][1] = w1 * inv;
    }
    __syncthreads();

    const int h = t >> 4;
    const float w0 = wtab[h][0], w1 = wtab[h][1];
    const size_t basei = (size_t)row * NE + t * 4;
    const bf4_t o0 = *(const bf4_t*)&oPart[basei];
    const bf4_t o1 = *(const bf4_t*)&oPart[(size_t)MTOT * NE + basei];
    float4 rr = *(const float4*)(resid + basei);
    float4 x;
    x.x = w0 * b2f(o0[0]) + w1 * b2f(o1[0]) + rr.x;
    x.y = w0 * b2f(o0[1]) + w1 * b2f(o1[1]) + rr.y;
    x.z = w0 * b2f(o0[2]) + w1 * b2f(o1[2]) + rr.z;
    x.w = w0 * b2f(o0[3]) + w1 * b2f(o1[3]) + rr.w;

    float ps = x.x + x.y + x.z + x.w;
#pragma unroll
    for (int off = 32; off; off >>= 1) ps += __shfl_xor(ps, off);
    if ((t & 63) == 0) red[t >> 6] = ps;
    __syncthreads();
    const float mean = (red[0] + red[1] + red[2] + red[3]) * (1.0f / NE);
    const float dx0 = x.x - mean, dx1 = x.y - mean, dx2 = x.z - mean, dx3 = x.w - mean;
    float ss = dx0 * dx0 + dx1 * dx1 + dx2 * dx2 + dx3 * dx3;
#pragma unroll
    for (int off = 32; off; off >>= 1) ss += __shfl_xor(ss, off);
    if ((t & 63) == 0) red[4 + (t >> 6)] = ss;
    __syncthreads();
    const float stdv = sqrtf((red[4] + red[5] + red[6] + red[7]) * (1.0f / (NE - 1)));
    float4 sc = *(const float4*)(ln_scale + t * 4);
    float4 sh = *(const float4*)(ln_shift + t * 4);
    float4 o;
    o.x = sc.x * dx0 / (stdv + 1e-6f + sh.x);
    o.y = sc.y * dx1 / (stdv + 1e-6f + sh.y);
    o.z = sc.z * dx2 / (stdv + 1e-6f + sh.z);
    o.w = sc.w * dx3 / (stdv + 1e-6f + sh.w);
    *(float4*)(out + basei) = o;
}

extern "C" void kernel_launch(void* const* d_in, const int* in_sizes, int n_in,
                              void* d_out, int out_size, void* d_ws, size_t ws_size,
                              hipStream_t stream) {
    (void)in_sizes; (void)n_in; (void)out_size; (void)ws_size;
    const float* query    = (const float*)d_in[0];
    const float* key_in   = (const float*)d_in[1];
    const float* value_in = (const float*)d_in[2];
    const float* resid    = (const float*)d_in[3];
    const float* Wq = (const float*)d_in[4];
    const float* bq = (const float*)d_in[5];
    const float* Wk = (const float*)d_in[6];
    const float* bk = (const float*)d_in[7];
    const float* Wv = (const float*)d_in[8];
    const float* bv = (const float*)d_in[9];
    const float* ln_scale = (const float*)d_in[10];
    const float* ln_shift = (const float*)d_in[11];
    float* out = (float*)d_out;

    // workspace (peak 46 MB, proven):
    //   wt [0,6)   dead after proj; ml [0,1) aliases wt (written by attn, after proj)
    //   q [6,14)  k [14,22)  vT [22,30)  oPart [30,46) (2 x 8MB bf16)
    char* ws = (char*)d_ws;
    short* wt_ws  = (short*)ws;
    float2* ml_ws = (float2*)ws;
    short* q_ws   = (short*)(ws + (6u << 20));
    short* k_ws   = (short*)(ws + (14u << 20));
    short* vT_ws  = (short*)(ws + (22u << 20));
    short* oPart  = (short*)(ws + (30u << 20));

    wt_kernel<<<dim3(3 * NH, NE / 64), 256, 0, stream>>>(Wq, Wk, Wv, wt_ws);
    proj_kernel<<<dim3(MTOT / 128, NE / 128, 3), 256, 0, stream>>>(
        query, key_in, value_in, wt_ws, bq, bk, bv, q_ws, k_ws, vT_ws);
    attn_kernel<<<1024, 256, 0, stream>>>(q_ws, k_ws, vT_ws, oPart, ml_ws);
    ln_kernel<<<dim3(NB * NS), 256, 0, stream>>>(oPart, ml_ws, resid, ln_scale, ln_shift, out);
}